// Round 7
// baseline (1028.287 us; speedup 1.0000x reference)
//
#include <hip/hip_runtime.h>

#define NN 20000
#define NE 320000
#define NG 64
#define D 128
#define D3 384
#define NRBF 20
#define RBF_ROW 24       // fp32 per rbf row -> 96B, 16B-aligned
#define PI_F 3.14159265358979323846f
#define RCUT 10.0f

typedef unsigned int uint;
typedef unsigned short ushort;
typedef __attribute__((ext_vector_type(8))) short bf16x8;
typedef __attribute__((ext_vector_type(4))) float f32x4;

__device__ __forceinline__ float silu_f(float x) {
    return x / (1.0f + __expf(-x));
}
// bf16 (stored as ushort) -> f32
__device__ __forceinline__ float b2f(ushort u) {
    return __uint_as_float(((uint)u) << 16);
}
// f32 -> bf16 RNE
__device__ __forceinline__ ushort f2b(float f) {
    uint u = __float_as_uint(f);
    u = u + 0x7fffu + ((u >> 16) & 1u);
    return (ushort)(u >> 16);
}

// ---------------------------------------------------------------- init
__global__ __launch_bounds__(256) void init_all(
    const int* __restrict__ atype, const float* __restrict__ emb,
    float* __restrict__ s, float* __restrict__ v, float* __restrict__ g,
    int* __restrict__ deg, uint* __restrict__ vh_u, int* __restrict__ bcount)
{
    int idx = blockIdx.x * blockDim.x + threadIdx.x;
    int stride = gridDim.x * blockDim.x;
    if (idx < NN * D) {
        int n = idx >> 7, d = idx & 127;
        s[idx] = emb[atype[n] * D + d];
    }
    if (idx < NG * D) g[idx] = 0.0f;
    if (idx < NN) deg[idx] = 0;
    if (idx < 64) bcount[idx] = 0;
    for (int i = idx; i < NN * 3 * D; i += stride) v[i] = 0.0f;
    for (int i = idx; i < NN * D3 / 2; i += stride) vh_u[i] = 0u;   // vh = bf16 zeros
}

// ---------------------------------------------------------------- weight pack (phi MLP)
// W^T layout, bf16 hi/lo split: w1t[j][k] = split(w1[k][j]), w2t[j][k] = split(w2[k][j])
__global__ __launch_bounds__(256) void pack_phi_w(
    const float* __restrict__ w1, const float* __restrict__ w2,
    ushort* __restrict__ w1th, ushort* __restrict__ w1tl,
    ushort* __restrict__ w2th, ushort* __restrict__ w2tl)
{
    int idx = blockIdx.x * blockDim.x + threadIdx.x;
    if (idx < D * D) {
        int j = idx >> 7, k = idx & 127;
        float x = w1[k * D + j];
        ushort h = f2b(x);
        w1th[idx] = h;
        w1tl[idx] = f2b(x - b2f(h));
    }
    if (idx < D3 * D) {
        int j = idx >> 7, k = idx & 127;
        float x = w2[k * D3 + j];
        ushort h = f2b(x);
        w2th[idx] = h;
        w2tl[idx] = f2b(x - b2f(h));
    }
}

// ---------------------------------------------------------------- CSR build (by dst)
__global__ __launch_bounds__(256) void csr_count(
    const int* __restrict__ dst, int* __restrict__ deg)
{
    int e = blockIdx.x * blockDim.x + threadIdx.x;
    if (e < NE) atomicAdd(&deg[dst[e]], 1);
}

__global__ __launch_bounds__(1024) void csr_scan(
    const int* __restrict__ deg, int* __restrict__ offs, int* __restrict__ cursor)
{
    __shared__ int part[1024];
    int t = threadIdx.x;
    const int per = (NN + 1023) / 1024;  // 20
    int base = t * per;
    int sum = 0;
    for (int i = 0; i < per; i++) {
        int idx = base + i;
        if (idx < NN) sum += deg[idx];
    }
    part[t] = sum;
    __syncthreads();
    for (int off = 1; off < 1024; off <<= 1) {
        int vv = (t >= off) ? part[t - off] : 0;
        __syncthreads();
        part[t] += vv;
        __syncthreads();
    }
    int run = part[t] - sum;  // exclusive base
    for (int i = 0; i < per; i++) {
        int idx = base + i;
        if (idx < NN) {
            offs[idx] = run;
            cursor[idx] = run;
            run += deg[idx];
        }
    }
    if (t == 1023) offs[NN] = run;  // == NE
}

__global__ __launch_bounds__(256) void csr_scatter(
    const int* __restrict__ dst, int* __restrict__ cursor, int* __restrict__ eid)
{
    int e = blockIdx.x * blockDim.x + threadIdx.x;
    if (e < NE) {
        int p = atomicAdd(&cursor[dst[e]], 1);
        eid[p] = e;
    }
}

// ---------------------------------------------------------------- degree sort (counting)
__global__ __launch_bounds__(256) void dbucket(
    const int* __restrict__ deg, int* __restrict__ bcount)
{
    int n = blockIdx.x * blockDim.x + threadIdx.x;
    if (n < NN) {
        int b = deg[n]; if (b > 63) b = 63;
        atomicAdd(&bcount[b], 1);
    }
}

__global__ void dscan(const int* __restrict__ bcount, int* __restrict__ bpos)
{
    if (threadIdx.x == 0) {
        int run = 0;
        for (int b = 63; b >= 0; b--) { bpos[b] = run; run += bcount[b]; }  // descending degree
    }
}

__global__ __launch_bounds__(256) void dscatter(
    const int* __restrict__ deg, int* __restrict__ bpos, int* __restrict__ perm)
{
    int n = blockIdx.x * blockDim.x + threadIdx.x;
    if (n < NN) {
        int b = deg[n]; if (b > 63) b = 63;
        int p = atomicAdd(&bpos[b], 1);
        perm[p] = n;
    }
}

// ---------------------------------------------------------------- edge geometry
__global__ __launch_bounds__(256) void edge_geom(
    const float* __restrict__ evec,
    float* __restrict__ rbf, float4* __restrict__ geo)
{
    int e = blockIdx.x * blockDim.x + threadIdx.x;
    if (e >= NE) return;
    float x = evec[e * 3 + 0], y = evec[e * 3 + 1], z = evec[e * 3 + 2];
    float r = sqrtf(x * x + y * y + z * z);
    float inv = 1.0f / r;
    float f = (r < RCUT) ? 0.5f * (cosf(PI_F * r / RCUT) + 1.0f) : 0.0f;
    float4 g;
    g.x = x * inv; g.y = y * inv; g.z = z * inv; g.w = f;
    geo[e] = g;
    float base = PI_F * r / RCUT;
    float sf = inv * f;
    #pragma unroll
    for (int k = 0; k < NRBF; k++) {
        rbf[(size_t)e * RBF_ROW + k] = sinf((float)(k + 1) * base) * sf;
    }
}

// ---------------------------------------------------------------- phi MLP via MFMA bf16x3
// 4 waves/block, 16 rows per wave. A staged in LDS (pad 136 -> 2-way-free banks).
// A frag: row = lane&15, k = (lane>>4)*8 + e. B frag (from W^T): col = lane&15, same k.
// C/D: col = lane&15, row = (lane>>4)*4 + r  [m89 verified].
__global__ __launch_bounds__(256) void phi_mlp_mfma(
    const float* __restrict__ s,
    const ushort* __restrict__ w1th, const ushort* __restrict__ w1tl,
    const float* __restrict__ b1,
    const ushort* __restrict__ w2th, const ushort* __restrict__ w2tl,
    const float* __restrict__ b2,
    ushort* __restrict__ phi_h)
{
    __shared__ ushort ah[4][16][136];
    __shared__ ushort al[4][16][136];
    int wave = threadIdx.x >> 6, lane = threadIdx.x & 63;
    int r0 = (blockIdx.x * 4 + wave) * 16;
    bool act = (r0 < NN);

    // Phase A: stage s rows as bf16 hi/lo
    if (act) {
        #pragma unroll
        for (int t = 0; t < 8; t++) {
            int flat = t * 256 + lane * 4;
            int row = flat >> 7, col = flat & 127;
            float4 sv = *(const float4*)&s[(size_t)(r0 + row) * D + col];
            ushort h0 = f2b(sv.x), h1 = f2b(sv.y), h2 = f2b(sv.z), h3 = f2b(sv.w);
            ushort l0 = f2b(sv.x - b2f(h0)), l1 = f2b(sv.y - b2f(h1));
            ushort l2 = f2b(sv.z - b2f(h2)), l3 = f2b(sv.w - b2f(h3));
            uint2 ph; ph.x = (uint)h0 | ((uint)h1 << 16); ph.y = (uint)h2 | ((uint)h3 << 16);
            uint2 pl; pl.x = (uint)l0 | ((uint)l1 << 16); pl.y = (uint)l2 | ((uint)l3 << 16);
            *(uint2*)&ah[wave][row][col] = ph;
            *(uint2*)&al[wave][row][col] = pl;
        }
    }
    __syncthreads();

    int arow = lane & 15, kg = lane >> 4;
    bf16x8 aH[4], aL[4];
    if (act) {
        #pragma unroll
        for (int t = 0; t < 4; t++) {
            aH[t] = *(const bf16x8*)&ah[wave][arow][t * 32 + kg * 8];
            aL[t] = *(const bf16x8*)&al[wave][arow][t * 32 + kg * 8];
        }
    }
    __syncthreads();   // frags in regs; LDS now reusable for h

    // Phase C: layer 1 (N=128) -> h staged back into LDS as hi/lo
    if (act) {
        #pragma unroll
        for (int jb = 0; jb < 8; jb++) {
            f32x4 acc = {0.f, 0.f, 0.f, 0.f};
            #pragma unroll
            for (int t = 0; t < 4; t++) {
                bf16x8 bh = *(const bf16x8*)&w1th[(size_t)(jb * 16 + arow) * 128 + t * 32 + kg * 8];
                bf16x8 bl = *(const bf16x8*)&w1tl[(size_t)(jb * 16 + arow) * 128 + t * 32 + kg * 8];
                acc = __builtin_amdgcn_mfma_f32_16x16x32_bf16(aH[t], bh, acc, 0, 0, 0);
                acc = __builtin_amdgcn_mfma_f32_16x16x32_bf16(aH[t], bl, acc, 0, 0, 0);
                acc = __builtin_amdgcn_mfma_f32_16x16x32_bf16(aL[t], bh, acc, 0, 0, 0);
            }
            float bias = b1[jb * 16 + arow];
            #pragma unroll
            for (int r = 0; r < 4; r++) {
                float hv = silu_f(acc[r] + bias);
                ushort hh = f2b(hv);
                ah[wave][kg * 4 + r][jb * 16 + arow] = hh;
                al[wave][kg * 4 + r][jb * 16 + arow] = f2b(hv - b2f(hh));
            }
        }
    }
    __syncthreads();

    // Phase D: layer 2 (N=384), bf16 store
    if (act) {
        bf16x8 hH[4], hL[4];
        #pragma unroll
        for (int t = 0; t < 4; t++) {
            hH[t] = *(const bf16x8*)&ah[wave][arow][t * 32 + kg * 8];
            hL[t] = *(const bf16x8*)&al[wave][arow][t * 32 + kg * 8];
        }
        #pragma unroll
        for (int jb = 0; jb < 24; jb++) {
            f32x4 acc = {0.f, 0.f, 0.f, 0.f};
            #pragma unroll
            for (int t = 0; t < 4; t++) {
                bf16x8 bh = *(const bf16x8*)&w2th[(size_t)(jb * 16 + arow) * 128 + t * 32 + kg * 8];
                bf16x8 bl = *(const bf16x8*)&w2tl[(size_t)(jb * 16 + arow) * 128 + t * 32 + kg * 8];
                acc = __builtin_amdgcn_mfma_f32_16x16x32_bf16(hH[t], bh, acc, 0, 0, 0);
                acc = __builtin_amdgcn_mfma_f32_16x16x32_bf16(hH[t], bl, acc, 0, 0, 0);
                acc = __builtin_amdgcn_mfma_f32_16x16x32_bf16(hL[t], bh, acc, 0, 0, 0);
            }
            float bias = b2[jb * 16 + arow];
            #pragma unroll
            for (int r = 0; r < 4; r++) {
                phi_h[(size_t)(r0 + kg * 4 + r) * D3 + jb * 16 + arow] = f2b(acc[r] + bias);
            }
        }
    }
}

// ---------------------------------------------------------------- node gather (unchanged from R5)
__global__ __launch_bounds__(512)
__attribute__((amdgpu_waves_per_eu(4, 4)))
void node_gather(
    const int* __restrict__ eid, const int* __restrict__ offs,
    const int* __restrict__ perm, const int* __restrict__ src,
    const ushort* __restrict__ phi_h,
    const float* __restrict__ s_old, const float* __restrict__ v_old,
    const ushort* __restrict__ vh,
    const float* __restrict__ rbf, const float4* __restrict__ geo,
    const float* __restrict__ filt_w, const float* __restrict__ filt_b,
    float* __restrict__ s_new, float* __restrict__ v_new)
{
    int wave = threadIdx.x >> 6;
    int lane = threadIdx.x & 63;
    int widx = blockIdx.x * 4 + (wave >> 1);
    if (widx >= NN) return;
    int node = __builtin_amdgcn_readfirstlane(perm[widx]);
    int half = wave & 1;
    int d = half * 64 + lane;

    float wr0[NRBF], wr1[NRBF], wr2[NRBF];
    #pragma unroll
    for (int k = 0; k < NRBF; k++) {
        wr0[k] = filt_w[k * D3 + d];
        wr1[k] = filt_w[k * D3 + D + d];
        wr2[k] = filt_w[k * D3 + 2 * D + d];
    }
    float fb0 = filt_b[d], fb1 = filt_b[D + d], fb2 = filt_b[2 * D + d];
    int e0 = __builtin_amdgcn_readfirstlane(offs[node]);
    int e1 = __builtin_amdgcn_readfirstlane(offs[node + 1]);

    float acc_s = 0.f, av0 = 0.f, av1 = 0.f, av2 = 0.f;

    for (int i = e0; i < e1; i++) {
        int e  = __builtin_amdgcn_readfirstlane(eid[i]);
        int sn = __builtin_amdgcn_readfirstlane(src[e]);
        float4 g = geo[e];
        const float*  rp = rbf + (size_t)e * RBF_ROW;
        const ushort* pp = phi_h + (size_t)sn * D3 + d;
        const ushort* qv = vh + (size_t)sn * D3 + d;
        float p0 = b2f(pp[0]), p1 = b2f(pp[D]), p2 = b2f(pp[2 * D]);
        float v0 = b2f(qv[0]), v1 = b2f(qv[D]), v2 = b2f(qv[2 * D]);

        float W0 = g.w * fb0, W1 = g.w * fb1, W2 = g.w * fb2;
        #pragma unroll
        for (int k = 0; k < NRBF; k++) {
            float rk = rp[k];
            W0 += rk * wr0[k];
            W1 += rk * wr1[k];
            W2 += rk * wr2[k];
        }
        float m1 = p0 * W0, m2 = p1 * W1, m3 = p2 * W2;
        acc_s += m2;
        av0 += v0 * m1 + g.x * m3;
        av1 += v1 * m1 + g.y * m3;
        av2 += v2 * m1 + g.z * m3;
    }

    s_new[node * D + d] = s_old[node * D + d] + acc_s;
    v_new[(node * 3 + 0) * D + d] = v_old[(node * 3 + 0) * D + d] + av0;
    v_new[(node * 3 + 1) * D + d] = v_old[(node * 3 + 1) * D + d] + av1;
    v_new[(node * 3 + 2) * D + d] = v_old[(node * 3 + 2) * D + d] + av2;
}

// ---------------------------------------------------------------- fused U/V + update
// 4 nodes per 256-thread block. U,Vp,UV,Vn never touch global memory.
__global__ __launch_bounds__(256) void node_vupd(
    float* __restrict__ s, float* __restrict__ v, ushort* __restrict__ vh,
    const float* __restrict__ Uw, const float* __restrict__ Vw,
    const float* __restrict__ w1, const float* __restrict__ b1,
    const float* __restrict__ w2, const float* __restrict__ b2)
{
    __shared__ float vl[4][3][D];     // 6 KB
    __shared__ float xl[4][2 * D];    // 4 KB  [Vn | s]
    __shared__ float hl[4][D];        // 2 KB
    int j = threadIdx.x & 127;
    int half = threadIdx.x >> 7;
    int n0 = blockIdx.x * 4;

    for (int t = threadIdx.x; t < 4 * 3 * D; t += 256)
        vl[t / 384][(t / 128) % 3][t & 127] = v[(size_t)n0 * 384 + t];
    for (int t = threadIdx.x; t < 4 * D; t += 256)
        xl[t >> 7][D + (t & 127)] = s[(size_t)n0 * D + t];
    __syncthreads();

    // U, Vp for 2 nodes per thread
    float u[2][3] = {{0,0,0},{0,0,0}};
    float p[2][3] = {{0,0,0},{0,0,0}};
    for (int k = 0; k < D; k++) {
        float wu = Uw[k * D + j], wv = Vw[k * D + j];
        #pragma unroll
        for (int q = 0; q < 2; q++)
            #pragma unroll
            for (int i = 0; i < 3; i++) {
                float vv = vl[half * 2 + q][i][k];
                u[q][i] += vv * wu;
                p[q][i] += vv * wv;
            }
    }
    float uv[2];
    #pragma unroll
    for (int q = 0; q < 2; q++) {
        float d_ = 0.f, nn = 0.f;
        #pragma unroll
        for (int i = 0; i < 3; i++) { d_ += u[q][i] * p[q][i]; nn += p[q][i] * p[q][i]; }
        uv[q] = d_;
        xl[half * 2 + q][j] = sqrtf(nn);   // Vn
    }
    __syncthreads();

    // layer 1: h = silu([Vn,s] @ w1 + b1)
    float acc[2] = {b1[j], b1[j]};
    for (int k = 0; k < 2 * D; k++) {
        float w = w1[k * D + j];
        acc[0] += xl[half * 2 + 0][k] * w;
        acc[1] += xl[half * 2 + 1][k] * w;
    }
    hl[half * 2 + 0][j] = silu_f(acc[0]);
    hl[half * 2 + 1][j] = silu_f(acc[1]);
    __syncthreads();

    // layer 2 + epilogue
    float a0[2] = {b2[j], b2[j]};
    float a1[2] = {b2[D + j], b2[D + j]};
    float a2[2] = {b2[2 * D + j], b2[2 * D + j]};
    for (int k = 0; k < D; k++) {
        float wa = w2[k * D3 + j];
        float wb = w2[k * D3 + D + j];
        float wc = w2[k * D3 + 2 * D + j];
        #pragma unroll
        for (int q = 0; q < 2; q++) {
            float h = hl[half * 2 + q][k];
            a0[q] += h * wa; a1[q] += h * wb; a2[q] += h * wc;
        }
    }
    #pragma unroll
    for (int q = 0; q < 2; q++) {
        int n = n0 + half * 2 + q;
        s[(size_t)n * D + j] = xl[half * 2 + q][D + j] + a2[q] + uv[q] * a1[q];
        #pragma unroll
        for (int i = 0; i < 3; i++) {
            size_t idx = ((size_t)n * 3 + i) * D + j;
            float vf = vl[half * 2 + q][i][j] + u[q][i] * a0[q];
            v[idx] = vf;
            vh[idx] = f2b(vf);
        }
    }
}

// ---------------------------------------------------------------- graph segment sum
__global__ __launch_bounds__(128) void graph_sum(
    const float* __restrict__ s, const int* __restrict__ gi, float* __restrict__ g)
{
    int d = threadIdx.x;
    int n0 = blockIdx.x * 64;
    int n1 = n0 + 64; if (n1 > NN) n1 = NN;
    if (n0 >= NN) return;
    int cur = gi[n0];
    float acc = 0.0f;
    for (int n = n0; n < n1; n++) {
        int gn = gi[n];
        if (gn != cur) { atomicAdd(&g[cur * D + d], acc); acc = 0.0f; cur = gn; }
        acc += s[n * D + d];
    }
    atomicAdd(&g[cur * D + d], acc);
}

// ---------------------------------------------------------------- readout
__global__ __launch_bounds__(128) void out_mlp(
    const float* __restrict__ g,
    const float* __restrict__ w1, const float* __restrict__ b1,
    const float* __restrict__ w2, const float* __restrict__ b2,
    float* __restrict__ out)
{
    __shared__ float gl[D];
    __shared__ float red[2];
    int j = threadIdx.x;
    int gr = blockIdx.x;
    gl[j] = g[gr * D + j];
    __syncthreads();
    float acc = b1[j];
    for (int k = 0; k < D; k++) acc += gl[k] * w1[k * D + j];
    float h = silu_f(acc) * w2[j];
    #pragma unroll
    for (int off = 32; off >= 1; off >>= 1) h += __shfl_down(h, off);
    if ((j & 63) == 0) red[j >> 6] = h;
    __syncthreads();
    if (j == 0) out[gr] = red[0] + red[1] + b2[0];
}

// ================================================================ launch
extern "C" void kernel_launch(void* const* d_in, const int* in_sizes, int n_in,
                              void* d_out, int out_size, void* d_ws, size_t ws_size,
                              hipStream_t stream)
{
    const int*   edge_src   = (const int*)  d_in[0];
    const int*   edge_dst   = (const int*)  d_in[1];
    const float* edge_vec   = (const float*)d_in[2];
    const int*   atom_types = (const int*)  d_in[3];
    const int*   node_gi    = (const int*)  d_in[4];
    const float* embedding  = (const float*)d_in[5];
    const float* phi_w1     = (const float*)d_in[6];
    const float* phi_b1     = (const float*)d_in[7];
    const float* phi_w2     = (const float*)d_in[8];
    const float* phi_b2     = (const float*)d_in[9];
    const float* filt_w     = (const float*)d_in[10];
    const float* filt_b     = (const float*)d_in[11];
    const float* upd_w1     = (const float*)d_in[12];
    const float* upd_b1     = (const float*)d_in[13];
    const float* upd_w2     = (const float*)d_in[14];
    const float* upd_b2     = (const float*)d_in[15];
    const float* U_w        = (const float*)d_in[16];
    const float* V_w        = (const float*)d_in[17];
    const float* out_w1     = (const float*)d_in[18];
    const float* out_b1     = (const float*)d_in[19];
    const float* out_w2     = (const float*)d_in[20];
    const float* out_b2     = (const float*)d_in[21];

    float* ws = (float*)d_ws;
    size_t o = 0;
    float* s_a   = ws + o; o += (size_t)NN * D;
    float* s_b   = ws + o; o += (size_t)NN * D;
    float* v_a   = ws + o; o += (size_t)NN * 3 * D;
    float* v_b   = ws + o; o += (size_t)NN * 3 * D;
    float* phh_f = ws + o; o += (size_t)NN * D3 / 2;          // phi_h bf16
    float* rbf_f = ws + o; o += (size_t)NE * RBF_ROW;         // fp32, padded rows
    float* geo   = ws + o; o += (size_t)NE * 4;
    float* vh_f  = ws + o; o += (size_t)NN * D3 / 2;          // bf16 storage
    float* g     = ws + o; o += (size_t)NG * D;
    float* w1t_f = ws + o; o += (size_t)D * D;                // w1th+w1tl (2x ushort = 1x float)
    float* w2t_f = ws + o; o += (size_t)D3 * D;               // w2th+w2tl
    int* deg     = (int*)(ws + o); o += NN;
    int* offs    = (int*)(ws + o); o += NN + 1;
    int* cursor  = (int*)(ws + o); o += NN;
    int* perm    = (int*)(ws + o); o += NN;
    int* bcount  = (int*)(ws + o); o += 64;
    int* bpos    = (int*)(ws + o); o += 64;
    int* eidb    = (int*)(ws + o); o += NE;

    ushort* phi_h = (ushort*)phh_f;
    ushort* vh    = (ushort*)vh_f;
    ushort* w1th  = (ushort*)w1t_f;
    ushort* w1tl  = w1th + (size_t)D * D;
    ushort* w2th  = (ushort*)w2t_f;
    ushort* w2tl  = w2th + (size_t)D3 * D;

    init_all<<<NN * D / 256, 256, 0, stream>>>(atom_types, embedding, s_a, v_a, g,
                                               deg, (uint*)vh_f, bcount);
    pack_phi_w<<<(D3 * D + 255) / 256, 256, 0, stream>>>(phi_w1, phi_w2,
                                                         w1th, w1tl, w2th, w2tl);
    csr_count<<<(NE + 255) / 256, 256, 0, stream>>>(edge_dst, deg);
    csr_scan<<<1, 1024, 0, stream>>>(deg, offs, cursor);
    csr_scatter<<<(NE + 255) / 256, 256, 0, stream>>>(edge_dst, cursor, eidb);
    dbucket<<<(NN + 255) / 256, 256, 0, stream>>>(deg, bcount);
    dscan<<<1, 64, 0, stream>>>(bcount, bpos);
    dscatter<<<(NN + 255) / 256, 256, 0, stream>>>(deg, bpos, perm);
    edge_geom<<<(NE + 255) / 256, 256, 0, stream>>>(edge_vec, rbf_f, (float4*)geo);

    float *s_cur = s_a, *v_cur = v_a, *s_nxt = s_b, *v_nxt = v_b;
    for (int round = 0; round < 2; round++) {
        phi_mlp_mfma<<<(NN / 16 + 3) / 4, 256, 0, stream>>>(s_cur, w1th, w1tl, phi_b1,
                                                            w2th, w2tl, phi_b2, phi_h);
        node_gather<<<NN / 4, 512, 0, stream>>>(eidb, offs, perm, edge_src, phi_h,
                                                s_cur, v_cur, vh, rbf_f,
                                                (const float4*)geo, filt_w, filt_b,
                                                s_nxt, v_nxt);
        node_vupd<<<NN / 4, 256, 0, stream>>>(s_nxt, v_nxt, vh, U_w, V_w,
                                              upd_w1, upd_b1, upd_w2, upd_b2);
        float* ts = s_cur; s_cur = s_nxt; s_nxt = ts;
        float* tv = v_cur; v_cur = v_nxt; v_nxt = tv;
    }

    graph_sum<<<(NN + 63) / 64, 128, 0, stream>>>(s_cur, node_gi, g);
    out_mlp<<<NG, 128, 0, stream>>>(g, out_w1, out_b1, out_w2, out_b2, (float*)d_out);
}

// Round 8
// 865.047 us; speedup vs baseline: 1.1887x; 1.1887x over previous
//
#include <hip/hip_runtime.h>

#define NN 20000
#define NE 320000
#define NG 64
#define D 128
#define D3 384
#define NRBF 20
#define RBF_ROW 24       // fp32 per rbf row -> 96B, 16B-aligned
#define PI_F 3.14159265358979323846f
#define RCUT 10.0f

typedef unsigned int uint;
typedef unsigned short ushort;
typedef __attribute__((ext_vector_type(8))) short bf16x8;
typedef __attribute__((ext_vector_type(4))) float f32x4;

__device__ __forceinline__ float silu_f(float x) {
    return x / (1.0f + __expf(-x));
}
__device__ __forceinline__ float b2f(ushort u) {
    return __uint_as_float(((uint)u) << 16);
}
__device__ __forceinline__ ushort f2b(float f) {
    uint u = __float_as_uint(f);
    u = u + 0x7fffu + ((u >> 16) & 1u);
    return (ushort)(u >> 16);
}

#define MFMA3(acc, aH, aL, bH, bL)                                          \
    acc = __builtin_amdgcn_mfma_f32_16x16x32_bf16(aL, bH, acc, 0, 0, 0);    \
    acc = __builtin_amdgcn_mfma_f32_16x16x32_bf16(aH, bL, acc, 0, 0, 0);    \
    acc = __builtin_amdgcn_mfma_f32_16x16x32_bf16(aH, bH, acc, 0, 0, 0);

// ---------------------------------------------------------------- init
__global__ __launch_bounds__(256) void init_all(
    const int* __restrict__ atype, const float* __restrict__ emb,
    float* __restrict__ s, float* __restrict__ v, float* __restrict__ g,
    int* __restrict__ deg, uint* __restrict__ vh_u, int* __restrict__ bcount)
{
    int idx = blockIdx.x * blockDim.x + threadIdx.x;
    int stride = gridDim.x * blockDim.x;
    if (idx < NN * D) {
        int n = idx >> 7, d = idx & 127;
        s[idx] = emb[atype[n] * D + d];
    }
    if (idx < NG * D) g[idx] = 0.0f;
    if (idx < NN) deg[idx] = 0;
    if (idx < 64) bcount[idx] = 0;
    for (int i = idx; i < NN * 3 * D; i += stride) v[i] = 0.0f;
    for (int i = idx; i < NN * D3 / 2; i += stride) vh_u[i] = 0u;
}

// ---------------------------------------------------------------- weight pack: phi MLP
__global__ __launch_bounds__(256) void pack_phi_w(
    const float* __restrict__ w1, const float* __restrict__ w2,
    ushort* __restrict__ w1th, ushort* __restrict__ w1tl,
    ushort* __restrict__ w2th, ushort* __restrict__ w2tl)
{
    int idx = blockIdx.x * blockDim.x + threadIdx.x;
    if (idx < D * D) {
        int j = idx >> 7, k = idx & 127;
        float x = w1[k * D + j];
        ushort h = f2b(x);
        w1th[idx] = h;
        w1tl[idx] = f2b(x - b2f(h));
    }
    if (idx < D3 * D) {
        int j = idx >> 7, k = idx & 127;
        float x = w2[k * D3 + j];
        ushort h = f2b(x);
        w2th[idx] = h;
        w2tl[idx] = f2b(x - b2f(h));
    }
}

// ---------------------------------------------------------------- weight pack: update block
// uwt/vwt: [j*128+k] = W[k*D+j], hi at [0], lo at [D*D]
// u1t: [j*256+k] = w1[k*D+j], lo at [2*D*D]
// u2t: [j*128+k] = w2[k*D3+j], lo at [D3*D]
__global__ __launch_bounds__(256) void pack_upd_w(
    const float* __restrict__ Uw, const float* __restrict__ Vw,
    const float* __restrict__ w1, const float* __restrict__ w2,
    ushort* __restrict__ uwt, ushort* __restrict__ vwt,
    ushort* __restrict__ u1t, ushort* __restrict__ u2t)
{
    int idx = blockIdx.x * blockDim.x + threadIdx.x;
    if (idx < D * D) {
        int j = idx >> 7, k = idx & 127;
        float x = Uw[k * D + j];
        ushort h = f2b(x);
        uwt[idx] = h; uwt[D * D + idx] = f2b(x - b2f(h));
        float y = Vw[k * D + j];
        ushort g = f2b(y);
        vwt[idx] = g; vwt[D * D + idx] = f2b(y - b2f(g));
    }
    if (idx < 2 * D * D) {
        int j = idx >> 8, k = idx & 255;
        float x = w1[k * D + j];
        ushort h = f2b(x);
        u1t[idx] = h; u1t[2 * D * D + idx] = f2b(x - b2f(h));
    }
    if (idx < D3 * D) {
        int j = idx >> 7, k = idx & 127;
        float x = w2[k * D3 + j];
        ushort h = f2b(x);
        u2t[idx] = h; u2t[D3 * D + idx] = f2b(x - b2f(h));
    }
}

// ---------------------------------------------------------------- CSR build (by dst)
__global__ __launch_bounds__(256) void csr_count(
    const int* __restrict__ dst, int* __restrict__ deg)
{
    int e = blockIdx.x * blockDim.x + threadIdx.x;
    if (e < NE) atomicAdd(&deg[dst[e]], 1);
}

__global__ __launch_bounds__(1024) void csr_scan(
    const int* __restrict__ deg, int* __restrict__ offs, int* __restrict__ cursor)
{
    __shared__ int part[1024];
    int t = threadIdx.x;
    const int per = (NN + 1023) / 1024;  // 20
    int base = t * per;
    int sum = 0;
    for (int i = 0; i < per; i++) {
        int idx = base + i;
        if (idx < NN) sum += deg[idx];
    }
    part[t] = sum;
    __syncthreads();
    for (int off = 1; off < 1024; off <<= 1) {
        int vv = (t >= off) ? part[t - off] : 0;
        __syncthreads();
        part[t] += vv;
        __syncthreads();
    }
    int run = part[t] - sum;
    for (int i = 0; i < per; i++) {
        int idx = base + i;
        if (idx < NN) {
            offs[idx] = run;
            cursor[idx] = run;
            run += deg[idx];
        }
    }
    if (t == 1023) offs[NN] = run;
}

__global__ __launch_bounds__(256) void csr_scatter(
    const int* __restrict__ dst, int* __restrict__ cursor, int* __restrict__ eid)
{
    int e = blockIdx.x * blockDim.x + threadIdx.x;
    if (e < NE) {
        int p = atomicAdd(&cursor[dst[e]], 1);
        eid[p] = e;
    }
}

// ---------------------------------------------------------------- degree sort (counting)
__global__ __launch_bounds__(256) void dbucket(
    const int* __restrict__ deg, int* __restrict__ bcount)
{
    int n = blockIdx.x * blockDim.x + threadIdx.x;
    if (n < NN) {
        int b = deg[n]; if (b > 63) b = 63;
        atomicAdd(&bcount[b], 1);
    }
}

__global__ void dscan(const int* __restrict__ bcount, int* __restrict__ bpos)
{
    if (threadIdx.x == 0) {
        int run = 0;
        for (int b = 63; b >= 0; b--) { bpos[b] = run; run += bcount[b]; }
    }
}

__global__ __launch_bounds__(256) void dscatter(
    const int* __restrict__ deg, int* __restrict__ bpos, int* __restrict__ perm)
{
    int n = blockIdx.x * blockDim.x + threadIdx.x;
    if (n < NN) {
        int b = deg[n]; if (b > 63) b = 63;
        int p = atomicAdd(&bpos[b], 1);
        perm[p] = n;
    }
}

// ---------------------------------------------------------------- edge geometry
__global__ __launch_bounds__(256) void edge_geom(
    const float* __restrict__ evec,
    float* __restrict__ rbf, float4* __restrict__ geo)
{
    int e = blockIdx.x * blockDim.x + threadIdx.x;
    if (e >= NE) return;
    float x = evec[e * 3 + 0], y = evec[e * 3 + 1], z = evec[e * 3 + 2];
    float r = sqrtf(x * x + y * y + z * z);
    float inv = 1.0f / r;
    float f = (r < RCUT) ? 0.5f * (cosf(PI_F * r / RCUT) + 1.0f) : 0.0f;
    float4 g;
    g.x = x * inv; g.y = y * inv; g.z = z * inv; g.w = f;
    geo[e] = g;
    float base = PI_F * r / RCUT;
    float sf = inv * f;
    #pragma unroll
    for (int k = 0; k < NRBF; k++) {
        rbf[(size_t)e * RBF_ROW + k] = sinf((float)(k + 1) * base) * sf;
    }
}

// ---------------------------------------------------------------- phi MLP via MFMA bf16x3 (R6, verified)
__global__ __launch_bounds__(256) void phi_mlp_mfma(
    const float* __restrict__ s,
    const ushort* __restrict__ w1th, const ushort* __restrict__ w1tl,
    const float* __restrict__ b1,
    const ushort* __restrict__ w2th, const ushort* __restrict__ w2tl,
    const float* __restrict__ b2,
    ushort* __restrict__ phi_h)
{
    __shared__ ushort ah[4][16][136];
    __shared__ ushort al[4][16][136];
    int wave = threadIdx.x >> 6, lane = threadIdx.x & 63;
    int r0 = (blockIdx.x * 4 + wave) * 16;
    bool act = (r0 < NN);

    if (act) {
        #pragma unroll
        for (int t = 0; t < 8; t++) {
            int flat = t * 256 + lane * 4;
            int row = flat >> 7, col = flat & 127;
            float4 sv = *(const float4*)&s[(size_t)(r0 + row) * D + col];
            ushort h0 = f2b(sv.x), h1 = f2b(sv.y), h2 = f2b(sv.z), h3 = f2b(sv.w);
            ushort l0 = f2b(sv.x - b2f(h0)), l1 = f2b(sv.y - b2f(h1));
            ushort l2 = f2b(sv.z - b2f(h2)), l3 = f2b(sv.w - b2f(h3));
            uint2 ph; ph.x = (uint)h0 | ((uint)h1 << 16); ph.y = (uint)h2 | ((uint)h3 << 16);
            uint2 pl; pl.x = (uint)l0 | ((uint)l1 << 16); pl.y = (uint)l2 | ((uint)l3 << 16);
            *(uint2*)&ah[wave][row][col] = ph;
            *(uint2*)&al[wave][row][col] = pl;
        }
    }
    __syncthreads();

    int arow = lane & 15, kg = lane >> 4;
    bf16x8 aH[4], aL[4];
    if (act) {
        #pragma unroll
        for (int t = 0; t < 4; t++) {
            aH[t] = *(const bf16x8*)&ah[wave][arow][t * 32 + kg * 8];
            aL[t] = *(const bf16x8*)&al[wave][arow][t * 32 + kg * 8];
        }
    }
    __syncthreads();

    if (act) {
        #pragma unroll
        for (int jb = 0; jb < 8; jb++) {
            f32x4 acc = {0.f, 0.f, 0.f, 0.f};
            #pragma unroll
            for (int t = 0; t < 4; t++) {
                bf16x8 bh = *(const bf16x8*)&w1th[(size_t)(jb * 16 + arow) * 128 + t * 32 + kg * 8];
                bf16x8 bl = *(const bf16x8*)&w1tl[(size_t)(jb * 16 + arow) * 128 + t * 32 + kg * 8];
                acc = __builtin_amdgcn_mfma_f32_16x16x32_bf16(aH[t], bh, acc, 0, 0, 0);
                acc = __builtin_amdgcn_mfma_f32_16x16x32_bf16(aH[t], bl, acc, 0, 0, 0);
                acc = __builtin_amdgcn_mfma_f32_16x16x32_bf16(aL[t], bh, acc, 0, 0, 0);
            }
            float bias = b1[jb * 16 + arow];
            #pragma unroll
            for (int r = 0; r < 4; r++) {
                float hv = silu_f(acc[r] + bias);
                ushort hh = f2b(hv);
                ah[wave][kg * 4 + r][jb * 16 + arow] = hh;
                al[wave][kg * 4 + r][jb * 16 + arow] = f2b(hv - b2f(hh));
            }
        }
    }
    __syncthreads();

    if (act) {
        bf16x8 hH[4], hL[4];
        #pragma unroll
        for (int t = 0; t < 4; t++) {
            hH[t] = *(const bf16x8*)&ah[wave][arow][t * 32 + kg * 8];
            hL[t] = *(const bf16x8*)&al[wave][arow][t * 32 + kg * 8];
        }
        #pragma unroll
        for (int jb = 0; jb < 24; jb++) {
            f32x4 acc = {0.f, 0.f, 0.f, 0.f};
            #pragma unroll
            for (int t = 0; t < 4; t++) {
                bf16x8 bh = *(const bf16x8*)&w2th[(size_t)(jb * 16 + arow) * 128 + t * 32 + kg * 8];
                bf16x8 bl = *(const bf16x8*)&w2tl[(size_t)(jb * 16 + arow) * 128 + t * 32 + kg * 8];
                acc = __builtin_amdgcn_mfma_f32_16x16x32_bf16(hH[t], bh, acc, 0, 0, 0);
                acc = __builtin_amdgcn_mfma_f32_16x16x32_bf16(hH[t], bl, acc, 0, 0, 0);
                acc = __builtin_amdgcn_mfma_f32_16x16x32_bf16(hL[t], bh, acc, 0, 0, 0);
            }
            float bias = b2[jb * 16 + arow];
            #pragma unroll
            for (int r = 0; r < 4; r++) {
                phi_h[(size_t)(r0 + kg * 4 + r) * D3 + jb * 16 + arow] = f2b(acc[r] + bias);
            }
        }
    }
}

// ---------------------------------------------------------------- node gather (R5, verified)
__global__ __launch_bounds__(512)
__attribute__((amdgpu_waves_per_eu(4, 4)))
void node_gather(
    const int* __restrict__ eid, const int* __restrict__ offs,
    const int* __restrict__ perm, const int* __restrict__ src,
    const ushort* __restrict__ phi_h,
    const float* __restrict__ s_old, const float* __restrict__ v_old,
    const ushort* __restrict__ vh,
    const float* __restrict__ rbf, const float4* __restrict__ geo,
    const float* __restrict__ filt_w, const float* __restrict__ filt_b,
    float* __restrict__ s_new, float* __restrict__ v_new)
{
    int wave = threadIdx.x >> 6;
    int lane = threadIdx.x & 63;
    int widx = blockIdx.x * 4 + (wave >> 1);
    if (widx >= NN) return;
    int node = __builtin_amdgcn_readfirstlane(perm[widx]);
    int half = wave & 1;
    int d = half * 64 + lane;

    float wr0[NRBF], wr1[NRBF], wr2[NRBF];
    #pragma unroll
    for (int k = 0; k < NRBF; k++) {
        wr0[k] = filt_w[k * D3 + d];
        wr1[k] = filt_w[k * D3 + D + d];
        wr2[k] = filt_w[k * D3 + 2 * D + d];
    }
    float fb0 = filt_b[d], fb1 = filt_b[D + d], fb2 = filt_b[2 * D + d];
    int e0 = __builtin_amdgcn_readfirstlane(offs[node]);
    int e1 = __builtin_amdgcn_readfirstlane(offs[node + 1]);

    float acc_s = 0.f, av0 = 0.f, av1 = 0.f, av2 = 0.f;

    for (int i = e0; i < e1; i++) {
        int e  = __builtin_amdgcn_readfirstlane(eid[i]);
        int sn = __builtin_amdgcn_readfirstlane(src[e]);
        float4 g = geo[e];
        const float*  rp = rbf + (size_t)e * RBF_ROW;
        const ushort* pp = phi_h + (size_t)sn * D3 + d;
        const ushort* qv = vh + (size_t)sn * D3 + d;
        float p0 = b2f(pp[0]), p1 = b2f(pp[D]), p2 = b2f(pp[2 * D]);
        float v0 = b2f(qv[0]), v1 = b2f(qv[D]), v2 = b2f(qv[2 * D]);

        float W0 = g.w * fb0, W1 = g.w * fb1, W2 = g.w * fb2;
        #pragma unroll
        for (int k = 0; k < NRBF; k++) {
            float rk = rp[k];
            W0 += rk * wr0[k];
            W1 += rk * wr1[k];
            W2 += rk * wr2[k];
        }
        float m1 = p0 * W0, m2 = p1 * W1, m3 = p2 * W2;
        acc_s += m2;
        av0 += v0 * m1 + g.x * m3;
        av1 += v1 * m1 + g.y * m3;
        av2 += v2 * m1 + g.z * m3;
    }

    s_new[node * D + d] = s_old[node * D + d] + acc_s;
    v_new[(node * 3 + 0) * D + d] = v_old[(node * 3 + 0) * D + d] + av0;
    v_new[(node * 3 + 1) * D + d] = v_old[(node * 3 + 1) * D + d] + av1;
    v_new[(node * 3 + 2) * D + d] = v_old[(node * 3 + 2) * D + d] + av2;
}

// ---------------------------------------------------------------- fused update via MFMA bf16x3
// 16 nodes per 256-thread block (4 waves). v staged as LDS rows [dir*16+node] so the
// 3 dirs of a node share (lane, reg) across m-tiles -> UV/Vn computed in registers.
// LDS phase plan (59904 B): U[48][132] f32 | UV[16][132] f32 | region B:
//   phase1 a_hi/a_lo[48][136]  ->  phase2 x_hi/x_lo[16][264] + h_hi/h_lo[16][136]
//   -> phase3 a_out[16][392] f32 (overlaps x/h after barrier)
__global__ __launch_bounds__(256) void node_vupd_mfma(
    float* __restrict__ s, float* __restrict__ v, ushort* __restrict__ vh,
    const ushort* __restrict__ uwt, const ushort* __restrict__ vwt,
    const ushort* __restrict__ u1t, const ushort* __restrict__ u2t,
    const float* __restrict__ b1, const float* __restrict__ b2)
{
    __shared__ __align__(16) char smem[59904];
    float*  U_lds  = (float*)(smem);             // [48][132]
    float*  UV_lds = (float*)(smem + 25344);     // [16][132]
    ushort* a_hi   = (ushort*)(smem + 33792);    // [48][136]
    ushort* a_lo   = a_hi + 48 * 136;
    ushort* x_hi   = (ushort*)(smem + 33792);    // [16][264]
    ushort* x_lo   = x_hi + 16 * 264;
    ushort* h_hi   = x_lo + 16 * 264;            // [16][136]
    ushort* h_lo   = h_hi + 16 * 136;
    float*  a_out  = (float*)(smem + 33792);     // [16][392]

    int tid = threadIdx.x;
    int wave = tid >> 6, lane = tid & 63;
    int arow = lane & 15, kg = lane >> 4;
    int n0 = blockIdx.x * 16;

    // ---- phase 1: stage v rows (dir-major) as bf16 hi/lo
    #pragma unroll
    for (int it = 0; it < 6; it++) {
        int f4 = it * 256 + tid;          // float4 units, 48*32 total
        int row = f4 >> 5;
        int c4 = (f4 & 31) * 4;
        int i = row >> 4, n = row & 15;
        float4 vv = *(const float4*)&v[((size_t)(n0 + n) * 3 + i) * D + c4];
        ushort h0 = f2b(vv.x), h1 = f2b(vv.y), h2 = f2b(vv.z), h3 = f2b(vv.w);
        ushort l0 = f2b(vv.x - b2f(h0)), l1 = f2b(vv.y - b2f(h1));
        ushort l2 = f2b(vv.z - b2f(h2)), l3 = f2b(vv.w - b2f(h3));
        uint2 ph; ph.x = (uint)h0 | ((uint)h1 << 16); ph.y = (uint)h2 | ((uint)h3 << 16);
        uint2 pl; pl.x = (uint)l0 | ((uint)l1 << 16); pl.y = (uint)l2 | ((uint)l3 << 16);
        *(uint2*)&a_hi[row * 136 + c4] = ph;
        *(uint2*)&a_lo[row * 136 + c4] = pl;
    }
    __syncthreads();

    // ---- phase 2: U = v@Uw, Vp = v@Vw via MFMA
    f32x4 accU[3][2], accVp[3][2];
    #pragma unroll
    for (int i = 0; i < 3; i++)
        #pragma unroll
        for (int jtl = 0; jtl < 2; jtl++) {
            accU[i][jtl] = (f32x4){0.f, 0.f, 0.f, 0.f};
            accVp[i][jtl] = (f32x4){0.f, 0.f, 0.f, 0.f};
        }
    #pragma unroll
    for (int i = 0; i < 3; i++) {
        #pragma unroll
        for (int t = 0; t < 4; t++) {
            bf16x8 aH = *(const bf16x8*)&a_hi[(i * 16 + arow) * 136 + t * 32 + kg * 8];
            bf16x8 aL = *(const bf16x8*)&a_lo[(i * 16 + arow) * 136 + t * 32 + kg * 8];
            #pragma unroll
            for (int jtl = 0; jtl < 2; jtl++) {
                int j = (wave * 2 + jtl) * 16 + arow;
                bf16x8 bH = *(const bf16x8*)&uwt[(size_t)j * 128 + t * 32 + kg * 8];
                bf16x8 bL = *(const bf16x8*)&uwt[(size_t)D * D + (size_t)j * 128 + t * 32 + kg * 8];
                MFMA3(accU[i][jtl], aH, aL, bH, bL)
                bf16x8 cH = *(const bf16x8*)&vwt[(size_t)j * 128 + t * 32 + kg * 8];
                bf16x8 cL = *(const bf16x8*)&vwt[(size_t)D * D + (size_t)j * 128 + t * 32 + kg * 8];
                MFMA3(accVp[i][jtl], aH, aL, cH, cL)
            }
        }
    }
    __syncthreads();   // all reads of a_hi/a_lo done; region B reusable

    // ---- write U, UV, Vn(->x); stage s(->x)
    #pragma unroll
    for (int jtl = 0; jtl < 2; jtl++) {
        int jcol = (wave * 2 + jtl) * 16 + arow;
        #pragma unroll
        for (int r = 0; r < 4; r++) {
            int n = kg * 4 + r;
            #pragma unroll
            for (int i = 0; i < 3; i++)
                U_lds[(i * 16 + n) * 132 + jcol] = accU[i][jtl][r];
            float uv = accU[0][jtl][r] * accVp[0][jtl][r]
                     + accU[1][jtl][r] * accVp[1][jtl][r]
                     + accU[2][jtl][r] * accVp[2][jtl][r];
            float nn = accVp[0][jtl][r] * accVp[0][jtl][r]
                     + accVp[1][jtl][r] * accVp[1][jtl][r]
                     + accVp[2][jtl][r] * accVp[2][jtl][r];
            UV_lds[n * 132 + jcol] = uv;
            float vn = sqrtf(nn);
            ushort hh = f2b(vn);
            x_hi[n * 264 + jcol] = hh;
            x_lo[n * 264 + jcol] = f2b(vn - b2f(hh));
        }
    }
    for (int t8 = tid; t8 < 16 * 128; t8 += 256) {
        int n = t8 >> 7, j = t8 & 127;
        float sv = s[(size_t)(n0 + n) * D + j];
        ushort hh = f2b(sv);
        x_hi[n * 264 + 128 + j] = hh;
        x_lo[n * 264 + 128 + j] = f2b(sv - b2f(hh));
    }
    __syncthreads();

    // ---- layer 1: h = silu(x @ w1 + b1), K=256
    {
        f32x4 acc1[2];
        acc1[0] = (f32x4){0.f, 0.f, 0.f, 0.f};
        acc1[1] = (f32x4){0.f, 0.f, 0.f, 0.f};
        #pragma unroll
        for (int t = 0; t < 8; t++) {
            bf16x8 aH = *(const bf16x8*)&x_hi[arow * 264 + t * 32 + kg * 8];
            bf16x8 aL = *(const bf16x8*)&x_lo[arow * 264 + t * 32 + kg * 8];
            #pragma unroll
            for (int jtl = 0; jtl < 2; jtl++) {
                int j = (wave * 2 + jtl) * 16 + arow;
                bf16x8 bH = *(const bf16x8*)&u1t[(size_t)j * 256 + t * 32 + kg * 8];
                bf16x8 bL = *(const bf16x8*)&u1t[(size_t)2 * D * D + (size_t)j * 256 + t * 32 + kg * 8];
                MFMA3(acc1[jtl], aH, aL, bH, bL)
            }
        }
        #pragma unroll
        for (int jtl = 0; jtl < 2; jtl++) {
            int j = (wave * 2 + jtl) * 16 + arow;
            float bias = b1[j];
            #pragma unroll
            for (int r = 0; r < 4; r++) {
                int n = kg * 4 + r;
                float hv = silu_f(acc1[jtl][r] + bias);
                ushort hh = f2b(hv);
                h_hi[n * 136 + j] = hh;
                h_lo[n * 136 + j] = f2b(hv - b2f(hh));
            }
        }
    }
    __syncthreads();

    // ---- layer 2: a = h @ w2 + b2, N=384
    f32x4 acc2[6];
    #pragma unroll
    for (int q = 0; q < 6; q++) acc2[q] = (f32x4){0.f, 0.f, 0.f, 0.f};
    #pragma unroll
    for (int t = 0; t < 4; t++) {
        bf16x8 aH = *(const bf16x8*)&h_hi[arow * 136 + t * 32 + kg * 8];
        bf16x8 aL = *(const bf16x8*)&h_lo[arow * 136 + t * 32 + kg * 8];
        #pragma unroll
        for (int q = 0; q < 6; q++) {
            int j = (wave * 6 + q) * 16 + arow;
            bf16x8 bH = *(const bf16x8*)&u2t[(size_t)j * 128 + t * 32 + kg * 8];
            bf16x8 bL = *(const bf16x8*)&u2t[(size_t)D3 * D + (size_t)j * 128 + t * 32 + kg * 8];
            MFMA3(acc2[q], aH, aL, bH, bL)
        }
    }
    __syncthreads();   // all reads of h done; a_out may overwrite

    #pragma unroll
    for (int q = 0; q < 6; q++) {
        int j = (wave * 6 + q) * 16 + arow;
        float bias = b2[j];
        #pragma unroll
        for (int r = 0; r < 4; r++)
            a_out[(kg * 4 + r) * 392 + j] = acc2[q][r] + bias;
    }
    __syncthreads();

    // ---- epilogue: s += ass + UV*asv ; v += U*avv ; vh = bf16(v)
    for (int t8 = tid; t8 < 16 * 128; t8 += 256) {
        int n = t8 >> 7, j = t8 & 127;
        float a0 = a_out[n * 392 + j];
        float a1 = a_out[n * 392 + 128 + j];
        float a2 = a_out[n * 392 + 256 + j];
        size_t sidx = (size_t)(n0 + n) * D + j;
        s[sidx] = s[sidx] + a2 + UV_lds[n * 132 + j] * a1;
        #pragma unroll
        for (int i = 0; i < 3; i++) {
            size_t idx = ((size_t)(n0 + n) * 3 + i) * D + j;
            float vf = v[idx] + U_lds[(i * 16 + n) * 132 + j] * a0;
            v[idx] = vf;
            vh[idx] = f2b(vf);
        }
    }
}

// ---------------------------------------------------------------- graph segment sum
__global__ __launch_bounds__(128) void graph_sum(
    const float* __restrict__ s, const int* __restrict__ gi, float* __restrict__ g)
{
    int d = threadIdx.x;
    int n0 = blockIdx.x * 64;
    int n1 = n0 + 64; if (n1 > NN) n1 = NN;
    if (n0 >= NN) return;
    int cur = gi[n0];
    float acc = 0.0f;
    for (int n = n0; n < n1; n++) {
        int gn = gi[n];
        if (gn != cur) { atomicAdd(&g[cur * D + d], acc); acc = 0.0f; cur = gn; }
        acc += s[n * D + d];
    }
    atomicAdd(&g[cur * D + d], acc);
}

// ---------------------------------------------------------------- readout
__global__ __launch_bounds__(128) void out_mlp(
    const float* __restrict__ g,
    const float* __restrict__ w1, const float* __restrict__ b1,
    const float* __restrict__ w2, const float* __restrict__ b2,
    float* __restrict__ out)
{
    __shared__ float gl[D];
    __shared__ float red[2];
    int j = threadIdx.x;
    int gr = blockIdx.x;
    gl[j] = g[gr * D + j];
    __syncthreads();
    float acc = b1[j];
    for (int k = 0; k < D; k++) acc += gl[k] * w1[k * D + j];
    float h = silu_f(acc) * w2[j];
    #pragma unroll
    for (int off = 32; off >= 1; off >>= 1) h += __shfl_down(h, off);
    if ((j & 63) == 0) red[j >> 6] = h;
    __syncthreads();
    if (j == 0) out[gr] = red[0] + red[1] + b2[0];
}

// ================================================================ launch
extern "C" void kernel_launch(void* const* d_in, const int* in_sizes, int n_in,
                              void* d_out, int out_size, void* d_ws, size_t ws_size,
                              hipStream_t stream)
{
    const int*   edge_src   = (const int*)  d_in[0];
    const int*   edge_dst   = (const int*)  d_in[1];
    const float* edge_vec   = (const float*)d_in[2];
    const int*   atom_types = (const int*)  d_in[3];
    const int*   node_gi    = (const int*)  d_in[4];
    const float* embedding  = (const float*)d_in[5];
    const float* phi_w1     = (const float*)d_in[6];
    const float* phi_b1     = (const float*)d_in[7];
    const float* phi_w2     = (const float*)d_in[8];
    const float* phi_b2     = (const float*)d_in[9];
    const float* filt_w     = (const float*)d_in[10];
    const float* filt_b     = (const float*)d_in[11];
    const float* upd_w1     = (const float*)d_in[12];
    const float* upd_b1     = (const float*)d_in[13];
    const float* upd_w2     = (const float*)d_in[14];
    const float* upd_b2     = (const float*)d_in[15];
    const float* U_w        = (const float*)d_in[16];
    const float* V_w        = (const float*)d_in[17];
    const float* out_w1     = (const float*)d_in[18];
    const float* out_b1     = (const float*)d_in[19];
    const float* out_w2     = (const float*)d_in[20];
    const float* out_b2     = (const float*)d_in[21];

    float* ws = (float*)d_ws;
    size_t o = 0;
    float* s_a   = ws + o; o += (size_t)NN * D;
    float* s_b   = ws + o; o += (size_t)NN * D;
    float* v_a   = ws + o; o += (size_t)NN * 3 * D;
    float* v_b   = ws + o; o += (size_t)NN * 3 * D;
    float* phh_f = ws + o; o += (size_t)NN * D3 / 2;          // phi_h bf16
    float* rbf_f = ws + o; o += (size_t)NE * RBF_ROW;         // fp32, padded rows
    float* geo   = ws + o; o += (size_t)NE * 4;
    float* vh_f  = ws + o; o += (size_t)NN * D3 / 2;          // bf16 storage
    float* g     = ws + o; o += (size_t)NG * D;
    float* w1t_f = ws + o; o += (size_t)D * D;                // phi w1 hi+lo
    float* w2t_f = ws + o; o += (size_t)D3 * D;               // phi w2 hi+lo
    float* uwt_f = ws + o; o += (size_t)D * D;                // Uw^T hi+lo
    float* vwt_f = ws + o; o += (size_t)D * D;                // Vw^T hi+lo
    float* u1t_f = ws + o; o += (size_t)2 * D * D;            // upd_w1^T hi+lo
    float* u2t_f = ws + o; o += (size_t)D3 * D;               // upd_w2^T hi+lo
    int* deg     = (int*)(ws + o); o += NN;
    int* offs    = (int*)(ws + o); o += NN + 1;
    int* cursor  = (int*)(ws + o); o += NN;
    int* perm    = (int*)(ws + o); o += NN;
    int* bcount  = (int*)(ws + o); o += 64;
    int* bpos    = (int*)(ws + o); o += 64;
    int* eidb    = (int*)(ws + o); o += NE;

    ushort* phi_h = (ushort*)phh_f;
    ushort* vh    = (ushort*)vh_f;
    ushort* w1th  = (ushort*)w1t_f;
    ushort* w1tl  = w1th + (size_t)D * D;
    ushort* w2th  = (ushort*)w2t_f;
    ushort* w2tl  = w2th + (size_t)D3 * D;
    ushort* uwt   = (ushort*)uwt_f;
    ushort* vwt   = (ushort*)vwt_f;
    ushort* u1t   = (ushort*)u1t_f;
    ushort* u2t   = (ushort*)u2t_f;

    init_all<<<NN * D / 256, 256, 0, stream>>>(atom_types, embedding, s_a, v_a, g,
                                               deg, (uint*)vh_f, bcount);
    pack_phi_w<<<(D3 * D + 255) / 256, 256, 0, stream>>>(phi_w1, phi_w2,
                                                         w1th, w1tl, w2th, w2tl);
    pack_upd_w<<<(D3 * D + 255) / 256, 256, 0, stream>>>(U_w, V_w, upd_w1, upd_w2,
                                                         uwt, vwt, u1t, u2t);
    csr_count<<<(NE + 255) / 256, 256, 0, stream>>>(edge_dst, deg);
    csr_scan<<<1, 1024, 0, stream>>>(deg, offs, cursor);
    csr_scatter<<<(NE + 255) / 256, 256, 0, stream>>>(edge_dst, cursor, eidb);
    dbucket<<<(NN + 255) / 256, 256, 0, stream>>>(deg, bcount);
    dscan<<<1, 64, 0, stream>>>(bcount, bpos);
    dscatter<<<(NN + 255) / 256, 256, 0, stream>>>(deg, bpos, perm);
    edge_geom<<<(NE + 255) / 256, 256, 0, stream>>>(edge_vec, rbf_f, (float4*)geo);

    float *s_cur = s_a, *v_cur = v_a, *s_nxt = s_b, *v_nxt = v_b;
    for (int round = 0; round < 2; round++) {
        phi_mlp_mfma<<<(NN / 16 + 3) / 4, 256, 0, stream>>>(s_cur, w1th, w1tl, phi_b1,
                                                            w2th, w2tl, phi_b2, phi_h);
        node_gather<<<NN / 4, 512, 0, stream>>>(eidb, offs, perm, edge_src, phi_h,
                                                s_cur, v_cur, vh, rbf_f,
                                                (const float4*)geo, filt_w, filt_b,
                                                s_nxt, v_nxt);
        node_vupd_mfma<<<NN / 16, 256, 0, stream>>>(s_nxt, v_nxt, vh,
                                                    uwt, vwt, u1t, u2t,
                                                    upd_b1, upd_b2);
        float* ts = s_cur; s_cur = s_nxt; s_nxt = ts;
        float* tv = v_cur; v_cur = v_nxt; v_nxt = tv;
    }

    graph_sum<<<(NN + 63) / 64, 128, 0, stream>>>(s_cur, node_gi, g);
    out_mlp<<<NG, 128, 0, stream>>>(g, out_w1, out_b1, out_w2, out_b2, (float*)d_out);
}